// Round 1
// 170.305 us; speedup vs baseline: 1.0970x; 1.0970x over previous
//
#include <hip/hip_runtime.h>
#include <hip/hip_bf16.h>

#define C 64          // C_IN == C_OUT == 64
#define BSH 7         // bucket shift: 128 nodes per bucket
#define BN  128       // nodes per bucket
#define NPART 8       // partitions == XCDs
#define PBUK 98       // buckets per partition (8*98=784 >= 782)
#define PS (PBUK*BN)  // nodes per partition = 12544
#define EPB 2048      // edges per block (256 thr x 8)
#define BCAP 2560     // bucket capacity (mean 2046, ~12 sigma)
#define PCAP 204800   // partition capacity (mean 200000, ~11 sigma)

typedef __attribute__((ext_vector_type(8))) short bh8;    // 8 bf16 (MFMA A/B frag)
typedef __attribute__((ext_vector_type(4))) float fx4;    // MFMA C/D frag
typedef __attribute__((ext_vector_type(2))) float fx2;
typedef __attribute__((ext_vector_type(4))) int   ix4;
typedef __attribute__((ext_vector_type(8))) unsigned short us8;

__device__ __forceinline__ unsigned short f2bf(float f) {  // RNE f32 -> bf16
    unsigned u = __float_as_uint(f);
    u += 0x7FFF + ((u >> 16) & 1);
    return (unsigned short)(u >> 16);
}
__device__ __forceinline__ float bf2f(unsigned short h) {
    return __uint_as_float(((unsigned)h) << 16);
}

// ---------------- 0: init: zero tickets + precompute split-bf16 W fragments ----------------
// Wf layout: bh8 at index ((t*2+h)*2+z)*64 + lane  (z=0 hi, z=1 lo) -> proj loads coalesced.
__global__ __launch_bounds__(256) void k_init(const float* __restrict__ W, int* __restrict__ tickets,
                                              int ntick, bh8* __restrict__ Wf) {
    int tid = threadIdx.x;
    for (int i = tid; i < ntick; i += 256) tickets[i] = 0;
    // 512 items: (t,h,lane) -> hi & lo frags
    for (int it = tid; it < 512; it += 256) {
        int lane = it & 63;
        int th = it >> 6;        // t*2+h, 0..7
        int t = th >> 1, h = th & 1;
        int m16 = lane & 15, q = lane >> 4;
        int n = t * 16 + m16;
        bh8 hi, lo;
#pragma unroll
        for (int j = 0; j < 8; j++) {
            int k = 32 * h + q * 8 + j;
            float w = W[k * 64 + n];
            unsigned short hb = f2bf(w);
            hi[j] = (short)hb;
            lo[j] = (short)f2bf(w - bf2f(hb));
        }
        Wf[(th * 2 + 0) * 64 + lane] = hi;
        Wf[(th * 2 + 1) * 64 + lane] = lo;
    }
}

// ---------------- 1: partition pass: bin edges into 8 partition regions (coalesced) --------
// pack = brel<<24 | trel<<17 | src
__global__ __launch_bounds__(256) void k_part(const int* __restrict__ row, const int* __restrict__ col,
                                              int* __restrict__ pcur, int* __restrict__ pp, int E) {
    __shared__ int h[NPART];
    __shared__ int cur[NPART];
    int tid = threadIdx.x;
    if (tid < NPART) h[tid] = 0;
    __syncthreads();

    int base = blockIdx.x * EPB + tid * 8;
    int cs[8], rs[8], pt[8];
    if (base + 8 <= E) {
        ix4 c0 = *(const ix4*)(col + base);
        ix4 c1 = *(const ix4*)(col + base + 4);
        ix4 r0 = *(const ix4*)(row + base);
        ix4 r1 = *(const ix4*)(row + base + 4);
#pragma unroll
        for (int i = 0; i < 4; i++) { cs[i] = c0[i]; cs[4 + i] = c1[i]; rs[i] = r0[i]; rs[4 + i] = r1[i]; }
    } else {
#pragma unroll
        for (int i = 0; i < 8; i++) {
            cs[i] = (base + i < E) ? col[base + i] : -1;
            rs[i] = (base + i < E) ? row[base + i] : 0;
        }
    }
#pragma unroll
    for (int i = 0; i < 8; i++) {
        int b = cs[i] >> BSH;
        pt[i] = (b * 669) >> 16;              // exact /98 for b<784
        if (cs[i] >= 0) atomicAdd(&h[pt[i]], 1);
    }
    __syncthreads();
    if (tid < NPART) {
        int c = h[tid];
        cur[tid] = (c > 0) ? atomicAdd(&pcur[tid], c) : 0;
    }
    __syncthreads();
#pragma unroll
    for (int i = 0; i < 8; i++) {
        if (cs[i] >= 0) {
            int p = pt[i];
            int b = cs[i] >> BSH;
            int brel = b - p * PBUK;
            int pos = atomicAdd(&cur[p], 1);
            if (pos < PCAP)
                pp[(size_t)p * PCAP + pos] = (brel << 24) | ((cs[i] & (BN - 1)) << 17) | rs[i];
        }
    }
}

// ---------------- 2: bucket pass (XCD-local): partition p -> its 98 bucket regions --------
__global__ __launch_bounds__(256) void k_sortscat3(const int* __restrict__ pp, const int* __restrict__ pcur,
                                                   int* __restrict__ bcur, int* __restrict__ pe) {
    __shared__ int h[PBUK];
    __shared__ int cur[PBUK];
    int p = blockIdx.x & (NPART - 1);
    int j = blockIdx.x >> 3;
    int tid = threadIdx.x;
    if (tid < PBUK) h[tid] = 0;
    __syncthreads();

    int cnt = pcur[p]; cnt = cnt < PCAP ? cnt : PCAP;
    int base = j * EPB + tid * 8;
    const int* src = pp + (size_t)p * PCAP;

    int v[8];
    if (base + 8 <= cnt) {
        ix4 a = *(const ix4*)(src + base);
        ix4 b = *(const ix4*)(src + base + 4);
#pragma unroll
        for (int i = 0; i < 4; i++) { v[i] = a[i]; v[4 + i] = b[i]; }
    } else {
#pragma unroll
        for (int i = 0; i < 8; i++) v[i] = (base + i < cnt) ? src[base + i] : -1;
    }
#pragma unroll
    for (int i = 0; i < 8; i++)
        if (v[i] >= 0) atomicAdd(&h[v[i] >> 24], 1);
    __syncthreads();
    if (tid < PBUK) {
        int c = h[tid];
        cur[tid] = (c > 0) ? atomicAdd(&bcur[p * PBUK + tid], c) : 0;
    }
    __syncthreads();
#pragma unroll
    for (int i = 0; i < 8; i++) {
        if (v[i] >= 0) {
            int brel = v[i] >> 24;
            int pos = atomicAdd(&cur[brel], 1);
            if (pos < BCAP)
                pe[(size_t)(p * PBUK + brel) * BCAP + pos] = v[i] & 0xFFFFFF;  // trel<<17|src
        }
    }
}

// ---------------- 3: fused bucket->CSR + MFMA projection for the bucket's 128 nodes --------
// Phase 1: count/scan/scatter (es, rowptr, deg; deg kept in LDS). Phase 2: y[r] = (x[r]@W)
// * rsqrt(deg+1) via split-bf16 MFMA, B-frags loaded precomputed (Wf), y stored via LDS
// stage as coalesced 16B/lane dwordx4.
__global__ __launch_bounds__(256) void k_sort2proj(const int* __restrict__ pe, const int* __restrict__ bcur,
                                                   int* __restrict__ es, int* __restrict__ rowptr,
                                                   int* __restrict__ deg, const float* __restrict__ x,
                                                   const bh8* __restrict__ Wf, unsigned short* __restrict__ y,
                                                   int N) {
    __shared__ int buf[BCAP];                     // 10 KB
    __shared__ int cnt[BN];
    __shared__ int cur[BN];
    __shared__ int dsh[BN];
    __shared__ unsigned short stage[4][32][C];    // 16 KB (per-wave private)

    int b = (blockIdx.x & (NPART - 1)) * PBUK + (blockIdx.x >> 3);  // bucket on its own XCD
    int tid = threadIdx.x;
    if (tid < BN) cnt[tid] = 0;
    __syncthreads();
    int m = bcur[b]; m = m < BCAP ? m : BCAP;
    size_t s0 = (size_t)b * BCAP;
    for (int e = tid; e < m; e += 256) {
        int p = pe[s0 + e];
        buf[e] = p;
        atomicAdd(&cnt[p >> 17], 1);
    }
    __syncthreads();
    int v = (tid < BN) ? cnt[tid] : 0;
    for (int off = 1; off < BN; off <<= 1) {
        int t = (tid < BN && tid >= off) ? cnt[tid - off] : 0;
        __syncthreads();
        if (tid < BN) cnt[tid] += t;
        __syncthreads();
    }
    if (tid < BN) {
        int excl = cnt[tid] - v;
        cur[tid] = (int)s0 + excl;
        dsh[tid] = v;
        int node = b * BN + tid;
        if (node < N) { rowptr[node] = (int)s0 + excl; deg[node] = v; }
    }
    __syncthreads();
    for (int e = tid; e < m; e += 256) {
        int p = buf[e];
        int pos = atomicAdd(&cur[p >> 17], 1);
        es[pos] = p & 0x1FFFF;
    }
    __syncthreads();

    // ---- phase 2: projection of nodes b*BN .. b*BN+127 ----
    int lane = tid & 63;
    int wave = tid >> 6;
    int m16 = lane & 15;
    int q   = lane >> 4;

    bh8 Bhi[4][2], Blo[4][2];
#pragma unroll
    for (int t = 0; t < 4; t++) {
#pragma unroll
        for (int h = 0; h < 2; h++) {
            Bhi[t][h] = Wf[((t * 2 + h) * 2 + 0) * 64 + lane];  // coalesced dwordx4
            Blo[t][h] = Wf[((t * 2 + h) * 2 + 1) * 64 + lane];
        }
    }

    int rowbase = b * BN + wave * 32;
#pragma unroll
    for (int tt = 0; tt < 2; tt++) {
        int m0 = rowbase + tt * 16;
        if (m0 < N) {
            int mrow = m0 + m16;
            int mc = mrow < N ? mrow : (N - 1);

            bh8 Ahi[2], Alo[2];
#pragma unroll
            for (int h = 0; h < 2; h++) {
                const fx4* p = (const fx4*)(x + (size_t)mc * C + 32 * h + q * 8);
                fx4 v0 = __builtin_nontemporal_load(p);
                fx4 v1 = __builtin_nontemporal_load(p + 1);
                float vs[8] = {v0[0], v0[1], v0[2], v0[3], v1[0], v1[1], v1[2], v1[3]};
#pragma unroll
                for (int j = 0; j < 8; j++) {
                    unsigned short hb = f2bf(vs[j]);
                    Ahi[h][j] = (short)hb;
                    Alo[h][j] = (short)f2bf(vs[j] - bf2f(hb));
                }
            }

            float dv[4];
#pragma unroll
            for (int r = 0; r < 4; r++) {
                int lr = wave * 32 + tt * 16 + q * 4 + r;  // local row
                dv[r] = rsqrtf((float)(dsh[lr] + 1));
            }

#pragma unroll
            for (int t = 0; t < 4; t++) {
                fx4 acc = {0.f, 0.f, 0.f, 0.f};
#pragma unroll
                for (int h = 0; h < 2; h++) {
                    acc = __builtin_amdgcn_mfma_f32_16x16x32_bf16(Ahi[h], Bhi[t][h], acc, 0, 0, 0);
                    acc = __builtin_amdgcn_mfma_f32_16x16x32_bf16(Ahi[h], Blo[t][h], acc, 0, 0, 0);
                    acc = __builtin_amdgcn_mfma_f32_16x16x32_bf16(Alo[h], Bhi[t][h], acc, 0, 0, 0);
                }
#pragma unroll
                for (int r = 0; r < 4; r++)
                    stage[wave][tt * 16 + q * 4 + r][t * 16 + m16] = f2bf(acc[r] * dv[r]);
            }
        }
    }
    // wave-local stage->global, 16 B/lane coalesced (same-wave LDS RAW: waitcnt only)
#pragma unroll
    for (int it = 0; it < 4; it++) {
        int lr = it * 8 + (lane >> 3);            // local row 0..31
        int ch = (lane & 7) * 8;                  // 8 ushorts
        int grow = rowbase + lr;
        if (grow < N)
            __builtin_nontemporal_store(*(const us8*)&stage[wave][lr][ch],
                                        (us8*)(y + (size_t)grow * C + ch));
    }
}

// ---------------- 4: aggregate: 2 nodes per wave (half-wave each), lane = channel-pair ----
// Each half-wave (32 lanes) owns one node; lane chd gathers the dword (bf16x2) holding
// channels 2*chd, 2*chd+1. One gather instr covers 2 edges (256 B payload); offsets are
// 32-bit (y spans 12.8 MB) so address math is a single mad_u24+shift, not 64-bit mul/addc.
// Per-channel accumulation order/tree is identical to the 1-node version -> bit-identical out.
#define BF2L(u) __uint_as_float((u) << 16)
#define BF2H(u) __uint_as_float((u) & 0xFFFF0000u)

__global__ __launch_bounds__(256) void k_aggregate(const int* __restrict__ rowptr, const int* __restrict__ deg,
                                                   const int* __restrict__ es, const unsigned short* __restrict__ y,
                                                   const float* __restrict__ b, float* __restrict__ out, int N) {
    int p = blockIdx.x & (NPART - 1);
    int j = blockIdx.x >> 3;
    int node = p * PS + j * 8 + (threadIdx.x >> 5);   // 8 nodes per block, 2 per wave
    int lim = (p + 1) * PS < N ? (p + 1) * PS : N;
    if (node >= lim) return;
    int chd = threadIdx.x & 31;                       // dword channel index 0..31

    const unsigned* yd = (const unsigned*)y;
    int m = deg[node];
    const int* sl = es + rowptr[node];

    unsigned us = yd[(unsigned)node * 32u + chd];     // self-loop
    float accL = BF2L(us);
    float accH = BF2H(us);

    int e = 0;
    while (e + 16 <= m) {
        ix4 a0 = *(const ix4*)(sl + e);
        ix4 a1 = *(const ix4*)(sl + e + 4);
        ix4 a2 = *(const ix4*)(sl + e + 8);
        ix4 a3 = *(const ix4*)(sl + e + 12);
        unsigned u0 = yd[(unsigned)a0[0] * 32u + chd], u1 = yd[(unsigned)a0[1] * 32u + chd];
        unsigned u2 = yd[(unsigned)a0[2] * 32u + chd], u3 = yd[(unsigned)a0[3] * 32u + chd];
        unsigned u4 = yd[(unsigned)a1[0] * 32u + chd], u5 = yd[(unsigned)a1[1] * 32u + chd];
        unsigned u6 = yd[(unsigned)a1[2] * 32u + chd], u7 = yd[(unsigned)a1[3] * 32u + chd];
        unsigned u8 = yd[(unsigned)a2[0] * 32u + chd], u9 = yd[(unsigned)a2[1] * 32u + chd];
        unsigned u10 = yd[(unsigned)a2[2] * 32u + chd], u11 = yd[(unsigned)a2[3] * 32u + chd];
        unsigned u12 = yd[(unsigned)a3[0] * 32u + chd], u13 = yd[(unsigned)a3[1] * 32u + chd];
        unsigned u14 = yd[(unsigned)a3[2] * 32u + chd], u15 = yd[(unsigned)a3[3] * 32u + chd];
        accL += ((BF2L(u0) + BF2L(u1)) + (BF2L(u2) + BF2L(u3))) +
                ((BF2L(u4) + BF2L(u5)) + (BF2L(u6) + BF2L(u7))) +
                ((BF2L(u8) + BF2L(u9)) + (BF2L(u10) + BF2L(u11))) +
                ((BF2L(u12) + BF2L(u13)) + (BF2L(u14) + BF2L(u15)));
        accH += ((BF2H(u0) + BF2H(u1)) + (BF2H(u2) + BF2H(u3))) +
                ((BF2H(u4) + BF2H(u5)) + (BF2H(u6) + BF2H(u7))) +
                ((BF2H(u8) + BF2H(u9)) + (BF2H(u10) + BF2H(u11))) +
                ((BF2H(u12) + BF2H(u13)) + (BF2H(u14) + BF2H(u15)));
        e += 16;
    }
    if (e + 8 <= m) {
        ix4 a0 = *(const ix4*)(sl + e);
        ix4 a1 = *(const ix4*)(sl + e + 4);
        unsigned u0 = yd[(unsigned)a0[0] * 32u + chd], u1 = yd[(unsigned)a0[1] * 32u + chd];
        unsigned u2 = yd[(unsigned)a0[2] * 32u + chd], u3 = yd[(unsigned)a0[3] * 32u + chd];
        unsigned u4 = yd[(unsigned)a1[0] * 32u + chd], u5 = yd[(unsigned)a1[1] * 32u + chd];
        unsigned u6 = yd[(unsigned)a1[2] * 32u + chd], u7 = yd[(unsigned)a1[3] * 32u + chd];
        accL += ((BF2L(u0) + BF2L(u1)) + (BF2L(u2) + BF2L(u3))) +
                ((BF2L(u4) + BF2L(u5)) + (BF2L(u6) + BF2L(u7)));
        accH += ((BF2H(u0) + BF2H(u1)) + (BF2H(u2) + BF2H(u3))) +
                ((BF2H(u4) + BF2H(u5)) + (BF2H(u6) + BF2H(u7)));
        e += 8;
    }
    if (e + 4 <= m) {
        ix4 a0 = *(const ix4*)(sl + e);
        unsigned u0 = yd[(unsigned)a0[0] * 32u + chd], u1 = yd[(unsigned)a0[1] * 32u + chd];
        unsigned u2 = yd[(unsigned)a0[2] * 32u + chd], u3 = yd[(unsigned)a0[3] * 32u + chd];
        accL += (BF2L(u0) + BF2L(u1)) + (BF2L(u2) + BF2L(u3));
        accH += (BF2H(u0) + BF2H(u1)) + (BF2H(u2) + BF2H(u3));
        e += 4;
    }
    while (e < m) {
        unsigned u = yd[(unsigned)sl[e] * 32u + chd];
        accL += BF2L(u);
        accH += BF2H(u);
        e++;
    }

    float dn = rsqrtf((float)(m + 1));
    fx2 bb = ((const fx2*)b)[chd];
    fx2 o2 = {dn * accL + bb.x, dn * accH + bb.y};
    __builtin_nontemporal_store(o2, (fx2*)out + (unsigned)node * 32u + chd);
}

extern "C" void kernel_launch(void* const* d_in, const int* in_sizes, int n_in,
                              void* d_out, int out_size, void* d_ws, size_t ws_size,
                              hipStream_t stream) {
    const float* x  = (const float*)d_in[0];
    const int*   ei = (const int*)d_in[1];
    const float* W  = (const float*)d_in[2];
    const float* b  = (const float*)d_in[3];
    float* out = (float*)d_out;

    const int N = in_sizes[0] / C;   // 100000
    const int E = in_sizes[1] / 2;   // 1600000
    const int* row = ei;             // sources
    const int* col = ei + E;         // targets

    const int nbukT = NPART * PBUK;          // 784
    const int nblk  = (E + EPB - 1) / EPB;   // 782

    // workspace: tickets(pcur+bcur) | deg | rowptr | Wf | pp | pe | es | y  (~37 MB)
    char* ws = (char*)d_ws;
    size_t o = 0;
    int* pcur   = (int*)(ws + o);
    int* bcur   = pcur + NPART;
    o += ((size_t)(NPART + nbukT) * 4 + 127) & ~(size_t)127;
    int* deg    = (int*)(ws + o); o += ((size_t)N * 4 + 127) & ~(size_t)127;
    int* rowptr = (int*)(ws + o); o += ((size_t)N * 4 + 127) & ~(size_t)127;
    bh8* Wf     = (bh8*)(ws + o); o += 16 * 64 * 16;
    int* pp     = (int*)(ws + o); o += ((size_t)NPART * PCAP * 4 + 127) & ~(size_t)127;
    int* pe     = (int*)(ws + o); o += ((size_t)nbukT * BCAP * 4 + 127) & ~(size_t)127;
    int* es     = (int*)(ws + o); o += ((size_t)nbukT * BCAP * 4 + 127) & ~(size_t)127;
    unsigned short* y = (unsigned short*)(ws + o);

    k_init<<<1, 256, 0, stream>>>(W, pcur, NPART + nbukT, Wf);
    k_part<<<nblk, 256, 0, stream>>>(row, col, pcur, pp, E);
    k_sortscat3<<<NPART * (PCAP / EPB), 256, 0, stream>>>(pp, pcur, bcur, pe);
    k_sort2proj<<<nbukT, 256, 0, stream>>>(pe, bcur, es, rowptr, deg, x, Wf, y, N);
    k_aggregate<<<NPART * (PS / 8), 256, 0, stream>>>(rowptr, deg, es, y, b, out, N);
}